// Round 4
// baseline (2144.574 us; speedup 1.0000x reference)
//
#include <hip/hip_runtime.h>
#include <hip/hip_bf16.h>

typedef short    bf16x8 __attribute__((ext_vector_type(8)));
typedef float    f32x4  __attribute__((ext_vector_type(4)));
typedef unsigned u32x4  __attribute__((ext_vector_type(4)));

#define RNN_H 128
#define RNN_T 2048
#define RNN_B 8192
#define RNN_C 10
#define BLK_N 32   // two 16-col tiles per block

template <typename D, typename S>
__device__ __forceinline__ D bitcast(const S& s) {
  static_assert(sizeof(D) == sizeof(S), "size mismatch");
  D d; __builtin_memcpy(&d, &s, sizeof(D)); return d;
}

__device__ __forceinline__ unsigned pk_bf16(float a0, float a1) {
  __hip_bfloat162 b2 = __float22bfloat162_rn(make_float2(a0, a1));
  unsigned u; __builtin_memcpy(&u, &b2, 4);
  return u;  // a0 in low 16, a1 in high 16
}

// setup-time RNE split for W: a ~= hi + lo, residual ~2^-17 |a|
__device__ __forceinline__ void split2(float a0, float a1, unsigned &hp, unsigned &lp) {
  hp = pk_bf16(a0, a1);
  float h0 = __uint_as_float(hp << 16);
  float h1 = __uint_as_float(hp & 0xffff0000u);
  lp = pk_bf16(a0 - h0, a1 - h1);
}

__device__ __forceinline__ float fast_tanh(float a) {
  // tanh(a) = 1 - 2/(exp(2a)+1)
  float e = __builtin_amdgcn_exp2f(a * 2.885390081777927f);
  return 1.0f - 2.0f * __builtin_amdgcn_rcpf(e + 1.0f);
}

__device__ __forceinline__ f32x4 mfma16(bf16x8 a, bf16x8 b, f32x4 c) {
  return __builtin_amdgcn_mfma_f32_16x16x32_bf16(a, b, c, 0, 0, 0);
}

// k-bijection for 16x16x32 frags (same map for A-load and B-store, so the true
// HW k-layout cancels): slot (g = lane>>4, j) -> k = 4*g + (j&3) + 16*(j>>2).
// Each thread's 8 C/D values (row = 16*mt + 4*g + r) form one lane-local
// bf16x8 B-slot -> single ds_write_b128 per hi/lo half.

__global__ __launch_bounds__(256, 1)
void rnn_fused(const float* __restrict__ x, const float* __restrict__ w_hx,
               const float* __restrict__ w_hh, const float* __restrict__ b_h,
               const float* __restrict__ w_ph, const float* __restrict__ b_p,
               float* __restrict__ out)
{
  // Single-buffered h per tile, B-frag order: [tile][hi/lo][kt(4)][lane(64)].
  // 16 KiB. Write->read pairs are barrier-separated by the 2-phase schedule.
  __shared__ bf16x8 hbuf[2][2][4][64];

  const int tid  = threadIdx.x;
  const int lane = tid & 63;
  const int wv   = tid >> 6;   // wave owns rows 32*wv .. 32*wv+31
  const int g    = lane >> 4;
  const int l15  = lane & 15;
  const int n0   = blockIdx.x * BLK_N;

  { // zero initial h for both tiles
    bf16x8 z = {0,0,0,0,0,0,0,0};
    bf16x8* p = &hbuf[0][0][0][0];
    for (int i = tid; i < 2*2*4*64; i += 256) p[i] = z;
  }

  // ---- W_hh hi/lo A-fragments, register-resident (64 VGPRs), shared by A/B ----
  bf16x8 Ahi[2][4], Alo[2][4];
  #pragma unroll
  for (int mt = 0; mt < 2; ++mt) {
    const float* wrow = w_hh + (size_t)(wv*32 + mt*16 + l15)*RNN_H + 4*g;
    #pragma unroll
    for (int kt = 0; kt < 4; ++kt) {
      f32x4 w0 = *(const f32x4*)(wrow + kt*32);        // j=0..3  (k off 0..3)
      f32x4 w1 = *(const f32x4*)(wrow + kt*32 + 16);   // j=4..7  (k off 16..19)
      unsigned h0,h1,h2,h3,l0,l1,l2,l3;
      split2(w0[0], w0[1], h0, l0);
      split2(w0[2], w0[3], h1, l1);
      split2(w1[0], w1[1], h2, l2);
      split2(w1[2], w1[3], h3, l3);
      u32x4 th = {h0,h1,h2,h3}, tl = {l0,l1,l2,l3};
      Ahi[mt][kt] = bitcast<bf16x8>(th);
      Alo[mt][kt] = bitcast<bf16x8>(tl);
    }
  }

  // bias / w_hx per C/D reg: m = wv*32 + mt*16 + 4*g + r
  f32x4 bh[2], wx[2];
  #pragma unroll
  for (int mt = 0; mt < 2; ++mt)
    #pragma unroll
    for (int r = 0; r < 4; ++r) {
      const int m = wv*32 + mt*16 + 4*g + r;
      bh[mt][r] = b_h[m];
      wx[mt][r] = w_hx[m];
    }

  // x streams for this lane's two batch columns (tile A, tile B)
  const float* pxA = x + (size_t)(n0 + l15) * RNN_T;
  const float* pxB = x + (size_t)(n0 + 16 + l15) * RNN_T;
  f32x4 xcA = *(const f32x4*)pxA;
  f32x4 xcB = *(const f32x4*)pxB;

  const f32x4 ZV = {0.0f, 0.0f, 0.0f, 0.0f};

  // accumulators for both tiles; B primed to zero so the first epi_B writes
  // h_B(0) = tanh(0) = 0.
  f32x4 cA0[2], cA1[2], cA2[2], cB0[2], cB1[2], cB2[2];
  #pragma unroll
  for (int mt = 0; mt < 2; ++mt) {
    cB0[mt] = ZV; cB1[mt] = ZV; cB2[mt] = ZV;
    cA0[mt] = ZV; cA1[mt] = ZV; cA2[mt] = ZV;
  }

  __syncthreads();

  // One phase: MFMA for tile RT (produce cM*) interleaved per-kt with the
  // epilogue of the other tile (consume cE*, write h into hbuf[WT]).
  auto phase = [&](int RT, int WT, float xv,
                   f32x4 (&cM0)[2], f32x4 (&cM1)[2], f32x4 (&cM2)[2],
                   f32x4 (&cE0)[2], f32x4 (&cE1)[2], f32x4 (&cE2)[2]) {
    #pragma unroll
    for (int mt = 0; mt < 2; ++mt)
      #pragma unroll
      for (int r = 0; r < 4; ++r)
        cM0[mt][r] = __builtin_fmaf(wx[mt][r], xv, bh[mt][r]);

    unsigned hw[4], lw[4];
    #pragma unroll
    for (int kt = 0; kt < 4; ++kt) {
      const bf16x8 bhv = hbuf[RT][0][kt][lane];
      const bf16x8 blv = hbuf[RT][1][kt][lane];
      cM0[0] = mfma16(Ahi[0][kt], bhv, cM0[0]);
      cM0[1] = mfma16(Ahi[1][kt], bhv, cM0[1]);
      cM1[0] = mfma16(Alo[0][kt], bhv, kt ? cM1[0] : ZV);
      cM1[1] = mfma16(Alo[1][kt], bhv, kt ? cM1[1] : ZV);
      cM2[0] = mfma16(Ahi[0][kt], blv, kt ? cM2[0] : ZV);
      cM2[1] = mfma16(Ahi[1][kt], blv, kt ? cM2[1] : ZV);
      { // epilogue chunk kt of the other tile (VALU, fills MFMA issue gaps)
        const int emt = kt >> 1, r0 = 2*(kt & 1);
        const float v0 = (cE0[emt][r0]   + cE1[emt][r0])   + cE2[emt][r0];
        const float v1 = (cE0[emt][r0+1] + cE1[emt][r0+1]) + cE2[emt][r0+1];
        const float t0 = fast_tanh(v0);
        const float t1 = fast_tanh(v1);
        const unsigned u0 = __float_as_uint(t0), u1 = __float_as_uint(t1);
        const unsigned hp = (u1 & 0xffff0000u) | (u0 >> 16);  // trunc-bf16 pack
        hw[kt] = hp;
        const float e0 = t0 - __uint_as_float(hp << 16);      // exact residual
        const float e1 = t1 - __uint_as_float(hp & 0xffff0000u);
        lw[kt] = pk_bf16(e0, e1);
      }
    }
    u32x4 a = {hw[0],hw[1],hw[2],hw[3]}, b = {lw[0],lw[1],lw[2],lw[3]};
    hbuf[WT][0][wv][lane] = bitcast<bf16x8>(a);
    hbuf[WT][1][wv][lane] = bitcast<bf16x8>(b);
    // LDS-only barrier (keep x prefetch vmcnt in flight)
    asm volatile("s_waitcnt lgkmcnt(0)\n\ts_barrier" ::: "memory");
  };

  for (int t4 = 0; t4 < RNN_T/4; ++t4) {
    f32x4 xnA = xcA, xnB = xcB;
    if (t4 + 1 < RNN_T/4) {
      xnA = *(const f32x4*)(pxA + 4*t4 + 4);
      xnB = *(const f32x4*)(pxB + 4*t4 + 4);
    }
    #pragma unroll
    for (int q = 0; q < 4; ++q) {
      // P1: MFMA_A(t) reads hbuf[0]=h_A(t); epi_B(t-1) writes hbuf[1]=h_B(t)
      phase(0, 1, xcA[q], cA0, cA1, cA2, cB0, cB1, cB2);
      // P2: MFMA_B(t) reads hbuf[1]=h_B(t); epi_A(t) writes hbuf[0]=h_A(t+1)
      phase(1, 0, xcB[q], cB0, cB1, cB2, cA0, cA1, cA2);
    }
    xcA = xnA; xcB = xnB;
  }

  // drain: tile B's last epilogue -> h_B(T) into hbuf[1]
  {
    unsigned hw[4], lw[4];
    #pragma unroll
    for (int w = 0; w < 4; ++w) {
      const int emt = w >> 1, r0 = 2*(w & 1);
      const float v0 = (cB0[emt][r0]   + cB1[emt][r0])   + cB2[emt][r0];
      const float v1 = (cB0[emt][r0+1] + cB1[emt][r0+1]) + cB2[emt][r0+1];
      const float t0 = fast_tanh(v0);
      const float t1 = fast_tanh(v1);
      const unsigned u0 = __float_as_uint(t0), u1 = __float_as_uint(t1);
      const unsigned hp = (u1 & 0xffff0000u) | (u0 >> 16);
      hw[w] = hp;
      const float e0 = t0 - __uint_as_float(hp << 16);
      const float e1 = t1 - __uint_as_float(hp & 0xffff0000u);
      lw[w] = pk_bf16(e0, e1);
    }
    u32x4 a = {hw[0],hw[1],hw[2],hw[3]}, b = {lw[0],lw[1],lw[2],lw[3]};
    hbuf[1][0][wv][lane] = bitcast<bf16x8>(a);
    hbuf[1][1][wv][lane] = bitcast<bf16x8>(b);
  }
  __syncthreads();

  // ---- projection: out[b][c] = w_ph[c,:] . h_last[:,b] + b_p[c] ----
  // h_A(T) in hbuf[0], h_B(T) in hbuf[1].
  #pragma unroll
  for (int pass = 0; pass < 2; ++pass) {
    const int idx = tid + pass*256;
    const int c   = idx >> 5;
    const int n32 = idx & 31;
    if (c < RNN_C) {
      const int tile = n32 >> 4;
      const int n    = n32 & 15;
      float sum = b_p[c];
      for (int k = 0; k < RNN_H; ++k) {
        const int kt = k >> 5;
        const int l  = 16*((k & 15) >> 2) + n;
        const int j  = (k & 3) + 4*((k >> 4) & 1);
        const unsigned short* ph = (const unsigned short*)&hbuf[tile][0][kt][l];
        const unsigned short* pl = (const unsigned short*)&hbuf[tile][1][kt][l];
        const float hv = __uint_as_float(((unsigned)ph[j]) << 16)
                       + __uint_as_float(((unsigned)pl[j]) << 16);
        sum = __builtin_fmaf(w_ph[c*RNN_H + k], hv, sum);
      }
      out[(size_t)(n0 + n32)*RNN_C + c] = sum;
    }
  }
}

extern "C" void kernel_launch(void* const* d_in, const int* in_sizes, int n_in,
                              void* d_out, int out_size, void* d_ws, size_t ws_size,
                              hipStream_t stream) {
  (void)in_sizes; (void)n_in; (void)out_size; (void)d_ws; (void)ws_size;
  const float* x    = (const float*)d_in[0];
  const float* w_hx = (const float*)d_in[1];
  const float* w_hh = (const float*)d_in[2];
  const float* b_h  = (const float*)d_in[3];
  const float* w_ph = (const float*)d_in[4];
  const float* b_p  = (const float*)d_in[5];
  float* out = (float*)d_out;
  rnn_fused<<<dim3(RNN_B/BLK_N), dim3(256), 0, stream>>>(x, w_hx, w_hh, b_h, w_ph, b_p, out);
}

// Round 5
// 1827.754 us; speedup vs baseline: 1.1733x; 1.1733x over previous
//
#include <hip/hip_runtime.h>
#include <hip/hip_bf16.h>

typedef short    bf16x8 __attribute__((ext_vector_type(8)));
typedef float    f32x4  __attribute__((ext_vector_type(4)));
typedef unsigned u32x4  __attribute__((ext_vector_type(4)));

#define RNN_H 128
#define RNN_T 2048
#define RNN_B 8192
#define RNN_C 10
#define BLK_N 32   // two 16-col tiles per block: A = waves 0-3, B = waves 4-7

template <typename D, typename S>
__device__ __forceinline__ D bitcast(const S& s) {
  static_assert(sizeof(D) == sizeof(S), "size mismatch");
  D d; __builtin_memcpy(&d, &s, sizeof(D)); return d;
}

__device__ __forceinline__ unsigned pk_bf16(float a0, float a1) {
  __hip_bfloat162 b2 = __float22bfloat162_rn(make_float2(a0, a1));
  unsigned u; __builtin_memcpy(&u, &b2, 4);
  return u;  // a0 in low 16, a1 in high 16
}

// setup-time RNE split for W: a ~= hi + lo, residual ~2^-17 |a|
__device__ __forceinline__ void split2(float a0, float a1, unsigned &hp, unsigned &lp) {
  hp = pk_bf16(a0, a1);
  float h0 = __uint_as_float(hp << 16);
  float h1 = __uint_as_float(hp & 0xffff0000u);
  lp = pk_bf16(a0 - h0, a1 - h1);
}

__device__ __forceinline__ float fast_tanh(float a) {
  // tanh(a) = 1 - 2/(exp(2a)+1)
  float e = __builtin_amdgcn_exp2f(a * 2.885390081777927f);
  return 1.0f - 2.0f * __builtin_amdgcn_rcpf(e + 1.0f);
}

__device__ __forceinline__ f32x4 mfma16(bf16x8 a, bf16x8 b, f32x4 c) {
  return __builtin_amdgcn_mfma_f32_16x16x32_bf16(a, b, c, 0, 0, 0);
}

// k-bijection for 16x16x32 frags (same map for A-load and B-store, so the true
// HW k-layout cancels): slot (g = lane>>4, j) -> k = 4*g + (j&3) + 16*(j>>2).
// Each thread's 8 C/D values (row = 16*mt + 4*g + r) form one lane-local
// bf16x8 B-slot -> single ds_write_b128 per hi/lo half.

// LDS-only barrier: drain ds ops (read AND write) so single-buffered h is
// safe across the barrier, but never drain vmcnt (x prefetch stays in flight).
#define BAR() asm volatile("s_waitcnt lgkmcnt(0)\n\ts_barrier" ::: "memory")

__global__ __launch_bounds__(512, 2)
void rnn_fused(const float* __restrict__ x, const float* __restrict__ w_hx,
               const float* __restrict__ w_hh, const float* __restrict__ b_h,
               const float* __restrict__ w_ph, const float* __restrict__ b_p,
               float* __restrict__ out)
{
  // Single-buffered h per tile, B-frag order: [tile][hi/lo][kt(4)][lane(64)].
  // 16 KiB. All write->read pairs cross a BAR() by the role schedule.
  __shared__ bf16x8 hbuf[2][2][4][64];

  const int tid  = threadIdx.x;
  const int lane = tid & 63;
  const int wv   = tid >> 6;   // 0..7
  const int grp  = wv >> 2;    // 0 = tile A, 1 = tile B
  const int wr   = wv & 3;     // row band: rows 32*wr .. 32*wr+31
  const int g    = lane >> 4;
  const int l15  = lane & 15;
  const int n0   = blockIdx.x * BLK_N;

  { // zero initial h for both tiles
    bf16x8 z = {0,0,0,0,0,0,0,0};
    bf16x8* p = &hbuf[0][0][0][0];
    for (int i = tid; i < 2*2*4*64; i += 512) p[i] = z;
  }

  // ---- W_hh hi/lo A-fragments, register-resident (64 VGPRs) ----
  bf16x8 Ahi[2][4], Alo[2][4];
  #pragma unroll
  for (int mt = 0; mt < 2; ++mt) {
    const float* wrow = w_hh + (size_t)(wr*32 + mt*16 + l15)*RNN_H + 4*g;
    #pragma unroll
    for (int kt = 0; kt < 4; ++kt) {
      f32x4 w0 = *(const f32x4*)(wrow + kt*32);        // j=0..3  (k off 0..3)
      f32x4 w1 = *(const f32x4*)(wrow + kt*32 + 16);   // j=4..7  (k off 16..19)
      unsigned h0,h1,h2,h3,l0,l1,l2,l3;
      split2(w0[0], w0[1], h0, l0);
      split2(w0[2], w0[3], h1, l1);
      split2(w1[0], w1[1], h2, l2);
      split2(w1[2], w1[3], h3, l3);
      u32x4 th = {h0,h1,h2,h3}, tl = {l0,l1,l2,l3};
      Ahi[mt][kt] = bitcast<bf16x8>(th);
      Alo[mt][kt] = bitcast<bf16x8>(tl);
    }
  }

  // bias / w_hx per C/D reg: m = wr*32 + mt*16 + 4*g + r
  f32x4 bh[2], wx[2];
  #pragma unroll
  for (int mt = 0; mt < 2; ++mt)
    #pragma unroll
    for (int r = 0; r < 4; ++r) {
      const int m = wr*32 + mt*16 + 4*g + r;
      bh[mt][r] = b_h[m];
      wx[mt][r] = w_hx[m];
    }

  // x stream for this wave's tile column
  const float* px = x + (size_t)(n0 + grp*16 + l15) * RNN_T;
  f32x4 xc = *(const f32x4*)px;

  const f32x4 ZV = {0.0f, 0.0f, 0.0f, 0.0f};

  // accumulators; primed to zero so tile B's first epilogue emits h_B(0)=0
  f32x4 c0[2], c1[2], c2[2];
  #pragma unroll
  for (int mt = 0; mt < 2; ++mt) { c0[mt] = ZV; c1[mt] = ZV; c2[mt] = ZV; }

  __syncthreads();

  // MFMA role: read own tile's h, produce pre-activation accumulators.
  auto mfma_tile = [&](float xv) {
    #pragma unroll
    for (int mt = 0; mt < 2; ++mt)
      #pragma unroll
      for (int r = 0; r < 4; ++r)
        c0[mt][r] = __builtin_fmaf(wx[mt][r], xv, bh[mt][r]);
    #pragma unroll
    for (int kt = 0; kt < 4; ++kt) {
      const bf16x8 bhv = hbuf[grp][0][kt][lane];
      const bf16x8 blv = hbuf[grp][1][kt][lane];
      c0[0] = mfma16(Ahi[0][kt], bhv, c0[0]);
      c0[1] = mfma16(Ahi[1][kt], bhv, c0[1]);
      c1[0] = mfma16(Alo[0][kt], bhv, kt ? c1[0] : ZV);
      c1[1] = mfma16(Alo[1][kt], bhv, kt ? c1[1] : ZV);
      c2[0] = mfma16(Ahi[0][kt], blv, kt ? c2[0] : ZV);
      c2[1] = mfma16(Ahi[1][kt], blv, kt ? c2[1] : ZV);
    }
  };

  // EPI role: merge chains, tanh, trunc-hi/RNE-lo split, write own tile's h.
  auto epi_tile = [&]() {
    unsigned hw[4], lw[4];
    #pragma unroll
    for (int w = 0; w < 4; ++w) {
      const int emt = w >> 1, r0 = 2*(w & 1);
      const float v0 = (c0[emt][r0]   + c1[emt][r0])   + c2[emt][r0];
      const float v1 = (c0[emt][r0+1] + c1[emt][r0+1]) + c2[emt][r0+1];
      const float t0 = fast_tanh(v0);
      const float t1 = fast_tanh(v1);
      const unsigned u0 = __float_as_uint(t0), u1 = __float_as_uint(t1);
      const unsigned hp = (u1 & 0xffff0000u) | (u0 >> 16);  // trunc-bf16 pack
      hw[w] = hp;
      const float e0 = t0 - __uint_as_float(hp << 16);      // exact residual
      const float e1 = t1 - __uint_as_float(hp & 0xffff0000u);
      lw[w] = pk_bf16(e0, e1);
    }
    u32x4 a = {hw[0],hw[1],hw[2],hw[3]}, b = {lw[0],lw[1],lw[2],lw[3]};
    hbuf[grp][0][wr][lane] = bitcast<bf16x8>(a);
    hbuf[grp][1][wr][lane] = bitcast<bf16x8>(b);
  };

  // Main loop. Interval 1: A does MFMA(t) while B does EPI -> h_B(t).
  //           Interval 2: A does EPI -> h_A(t+1) while B does MFMA(t).
  // Every SIMD holds one A-wave + one B-wave -> matrix and VALU pipes are
  // both fed in every interval, enforced by the barrier (not by luck).
  for (int t4 = 0; t4 < RNN_T/4; ++t4) {
    f32x4 xn = xc;
    if (t4 + 1 < RNN_T/4) xn = *(const f32x4*)(px + 4*t4 + 4);
    #pragma unroll
    for (int q = 0; q < 4; ++q) {
      if (grp == 0) mfma_tile(xc[q]); else epi_tile();
      BAR();
      if (grp == 0) epi_tile();      else mfma_tile(xc[q]);
      BAR();
    }
    xc = xn;
  }

  // drain: tile B's last epilogue -> h_B(T)
  if (grp == 1) epi_tile();
  __syncthreads();

  // ---- projection: out[b][c] = w_ph[c,:] . h_last[:,b] + b_p[c] ----
  {
    const int c   = tid >> 5;
    const int n32 = tid & 31;
    if (c < RNN_C) {
      const int tile = n32 >> 4;
      const int n    = n32 & 15;
      float sum = b_p[c];
      for (int k = 0; k < RNN_H; ++k) {
        const int kt = k >> 5;
        const int l  = 16*((k & 15) >> 2) + n;
        const int j  = (k & 3) + 4*((k >> 4) & 1);
        const unsigned short* ph = (const unsigned short*)&hbuf[tile][0][kt][l];
        const unsigned short* pl = (const unsigned short*)&hbuf[tile][1][kt][l];
        const float hv = __uint_as_float(((unsigned)ph[j]) << 16)
                       + __uint_as_float(((unsigned)pl[j]) << 16);
        sum = __builtin_fmaf(w_ph[c*RNN_H + k], hv, sum);
      }
      out[(size_t)(n0 + n32)*RNN_C + c] = sum;
    }
  }
}

extern "C" void kernel_launch(void* const* d_in, const int* in_sizes, int n_in,
                              void* d_out, int out_size, void* d_ws, size_t ws_size,
                              hipStream_t stream) {
  (void)in_sizes; (void)n_in; (void)out_size; (void)d_ws; (void)ws_size;
  const float* x    = (const float*)d_in[0];
  const float* w_hx = (const float*)d_in[1];
  const float* w_hh = (const float*)d_in[2];
  const float* b_h  = (const float*)d_in[3];
  const float* w_ph = (const float*)d_in[4];
  const float* b_p  = (const float*)d_in[5];
  float* out = (float*)d_out;
  rnn_fused<<<dim3(RNN_B/BLK_N), dim3(512), 0, stream>>>(x, w_hx, w_hh, b_h, w_ph, b_p, out);
}